// Round 4
// baseline (247.999 us; speedup 1.0000x reference)
//
#include <hip/hip_runtime.h>
#include <stdint.h>

// Problem constants (fixed by setup_inputs)
#define NROWS 8192
#define DDIM 256
#define NSTRIPS 16
#define STRIP_COLS 512                      // NROWS / NSTRIPS
#define BM 128                              // rows per block (4 waves x 32 rows)
#define GRIDMAIN (NSTRIPS * (NROWS / BM))   // 1024 blocks
#define NMERGE 32                           // last-arriving blocks that do the merge
#define MROWS (NROWS / NMERGE)              // 256 rows per merge block

// Scores are computed directly in log2-units: e is scaled by sqrt(log2(e)/0.7)
// so acc = s*log2(e) and exp(s) == exp2(acc). Since s <= 1/0.7, exp2(acc) <= 4.17:
// no overflow, so no log-sum-exp shift is needed anywhere.
#define ESCALE 1.4356159f        // sqrt(log2(e)/0.7)
#define LN2F   0.6931471806f
#define NEGBIG (-1e30f)

typedef __attribute__((ext_vector_type(8))) short short8;   // 8 bf16 = 4 VGPRs
typedef __attribute__((ext_vector_type(4))) float f32x4;    // MFMA 16x16 accumulator

__device__ __forceinline__ unsigned short f2bf(float x) {   // RNE float->bf16
  unsigned int u = __float_as_uint(x);
  u += 0x7fffu + ((u >> 16) & 1u);
  return (unsigned short)(u >> 16);
}

// ---------------- Kernel 1: row L2-normalize -> scaled bf16 (+ zero counters) ----------------
__global__ __launch_bounds__(256) void knorm(const float* __restrict__ emb,
                                             unsigned short* __restrict__ ebf,
                                             float* __restrict__ accv) {
  if (blockIdx.x == 0 && threadIdx.x < 4) accv[threadIdx.x] = 0.f;  // loss,cnt,ctr1,ctr2
  const int wave = threadIdx.x >> 6, lane = threadIdx.x & 63;
  const int row = blockIdx.x * 4 + wave;              // one wave per row
  const float4 v = *(const float4*)(emb + row * DDIM + lane * 4);
  float ss = v.x * v.x + v.y * v.y + v.z * v.z + v.w * v.w;
#pragma unroll
  for (int off = 1; off < 64; off <<= 1) ss += __shfl_xor(ss, off, 64);
  const float sc = rsqrtf(ss) * ESCALE;
  ushort4 o;
  o.x = f2bf(v.x * sc); o.y = f2bf(v.y * sc);
  o.z = f2bf(v.z * sc); o.w = f2bf(v.w * sc);
  *(ushort4*)(ebf + row * DDIM + lane * 4) = o;
}

// ---------------- Kernel 2: barrier-free fused sims + masks + tail merge ----------------
// grid = (NSTRIPS, NROWS/BM) = 1024 blocks; blockIdx.x%8 = XCD so each XCD's L2
// sees only 2 strips of B (512 KB). No LDS: B fragments are loaded straight from
// global in MFMA B-layout (16 B/lane, 16 lines/inst — same shape as the A load).
// Co-resident blocks on a CU (ids +-256 apart) share the same strip -> L1 reuse.
__global__ __launch_bounds__(256, 3) void kmain(const unsigned short* __restrict__ ebf,
                                                const int* __restrict__ cats,
                                                float* __restrict__ posP,
                                                float* __restrict__ sumP,
                                                float* __restrict__ accv,
                                                float* __restrict__ out) {
  const int tid = threadIdx.x;
  const int lane = tid & 63, wave = tid >> 6;
  const int lane15 = lane & 15, quad = lane >> 4;
  const int strip = blockIdx.x, rowTile = blockIdx.y;
  const int rowG = rowTile * BM + wave * 32;          // this wave's 32 rows (mt=2)
  const int col0 = strip * STRIP_COLS;

  // A fragments live in registers all kernel: A[m=lane&15][k=quad*8+j]
  short8 a[2][8];
#pragma unroll
  for (int m = 0; m < 2; ++m)
#pragma unroll
    for (int kk = 0; kk < 8; ++kk)
      a[m][kk] = *(const short8*)(ebf + (rowG + m * 16 + lane15) * DDIM + kk * 32 + quad * 8);

  // Per-lane C-layout row categories: row = quad*4 + r (+ m*16)
  int cati[2][4];
#pragma unroll
  for (int m = 0; m < 2; ++m)
#pragma unroll
    for (int r = 0; r < 4; ++r)
      cati[m][r] = cats[rowG + m * 16 + quad * 4 + r];

  float pm[2][4], ns[2][4];
#pragma unroll
  for (int m = 0; m < 2; ++m)
#pragma unroll
    for (int r = 0; r < 4; ++r) { pm[m][r] = NEGBIG; ns[m][r] = 0.f; }

  // B streaming pointers: per ct-tile of 16 cols advance 16*DDIM*2 = 8192 B;
  // the 8 k-chunk loads use immediate offsets kk*64.
  const char* bp = (const char*)(ebf + (size_t)(col0 + lane15) * DDIM + quad * 8);
  const int* cp = cats + col0 + lane15;

#pragma unroll 2
  for (int ct = 0; ct < STRIP_COLS / 16; ++ct) {
    const int cj = cp[ct * 16];                       // this tile's 16 col categories
    short8 b[8];
#pragma unroll
    for (int kk = 0; kk < 8; ++kk)
      b[kk] = *(const short8*)(bp + kk * 64);         // B[k=quad*8+j][n=lane15]
    bp += 16 * DDIM * 2;

    f32x4 acc0 = {0.f, 0.f, 0.f, 0.f}, acc1 = {0.f, 0.f, 0.f, 0.f};
#pragma unroll
    for (int kk = 0; kk < 8; ++kk) {
      acc0 = __builtin_amdgcn_mfma_f32_16x16x32_bf16(a[0][kk], b[kk], acc0, 0, 0, 0);
      acc1 = __builtin_amdgcn_mfma_f32_16x16x32_bf16(a[1][kk], b[kk], acc1, 0, 0, 0);
    }

    const int colBase = col0 + ct * 16;
#pragma unroll
    for (int m = 0; m < 2; ++m) {
      const bool dg = (rowG + m * 16 == colBase);     // wave-uniform: diagonal tile?
      float psv[4], ev[4];
#pragma unroll
      for (int r = 0; r < 4; ++r) {
        const float s = m ? acc1[r] : acc0[r];        // score in log2-units
        const bool same = (cj == cati[m][r]);
        psv[r] = same ? s : NEGBIG;                   // positive candidate
        ev[r] = same ? 0.f : __builtin_amdgcn_exp2f(s);  // negative exp
      }
      if (dg) {                                       // rare uniform branch: self-exclude
#pragma unroll
        for (int r = 0; r < 4; ++r)
          if (lane15 == quad * 4 + r) psv[r] = NEGBIG;
      }
#pragma unroll
      for (int r = 0; r < 4; ++r) {
        pm[m][r] = fmaxf(pm[m][r], psv[r]);
        ns[m][r] += ev[r];
      }
    }
  }

  // Reduce across the 16 lanes of each quad (they share rows quad*4+r).
#pragma unroll
  for (int off = 1; off < 16; off <<= 1) {
#pragma unroll
    for (int m = 0; m < 2; ++m)
#pragma unroll
      for (int r = 0; r < 4; ++r) {
        pm[m][r] = fmaxf(pm[m][r], __shfl_xor(pm[m][r], off, 64));
        ns[m][r] += __shfl_xor(ns[m][r], off, 64);
      }
  }
  if (lane15 == 0) {
#pragma unroll
    for (int m = 0; m < 2; ++m)
#pragma unroll
      for (int r = 0; r < 4; ++r) {
        const int row = rowG + m * 16 + quad * 4 + r;
        posP[strip * NROWS + row] = pm[m][r];
        sumP[strip * NROWS + row] = ns[m][r];
      }
  }

  // ---- tail: last NMERGE arriving blocks merge strips and finalize ----
  __shared__ int sPrev;
  __syncthreads();                        // all partial stores issued block-wide
  if (tid == 0) {
    __threadfence();                      // release partials device-wide
    sPrev = atomicAdd((int*)(accv + 2), 1);
  }
  __syncthreads();
  const int prev = sPrev;
  if (prev < GRIDMAIN - NMERGE) return;   // early blocks exit
  const int rank = prev - (GRIDMAIN - NMERGE);
  if (tid == 0) {
    while (atomicAdd((int*)(accv + 2), 0) < GRIDMAIN) __builtin_amdgcn_s_sleep(2);
  }
  __syncthreads();
  __threadfence();

  const int row = rank * MROWS + tid;     // MROWS == blockDim.x == 256
  float pmv = NEGBIG, nsv = 0.f;
#pragma unroll
  for (int s = 0; s < NSTRIPS; ++s) {     // atomic reads: coherent across XCDs
    pmv = fmaxf(pmv, atomicAdd(posP + s * NROWS + row, 0.f));
    nsv += atomicAdd(sumP + s * NROWS + row, 0.f);
  }
  const bool valid = (pmv > -1e29f) && (nsv > 0.f);
  // pmv is pos*log2(e); loss = ln(exp2(pmv) + sum_neg) - pmv*ln2
  float loss = valid ? (logf(__builtin_amdgcn_exp2f(pmv) + nsv) - pmv * LN2F) : 0.f;
  float cnt = valid ? 1.f : 0.f;
#pragma unroll
  for (int off = 1; off < 64; off <<= 1) {
    loss += __shfl_xor(loss, off, 64);
    cnt += __shfl_xor(cnt, off, 64);
  }
  if (lane == 0) {
    atomicAdd(&accv[0], loss);
    atomicAdd(&accv[1], cnt);
  }
  __syncthreads();
  if (tid == 0) {
    __threadfence();
    const int p2 = atomicAdd((int*)(accv + 3), 1);
    if (p2 == NMERGE - 1) {               // very last block writes the scalar
      const float L = atomicAdd(&accv[0], 0.f);
      const float C = atomicAdd(&accv[1], 0.f);
      out[0] = L / fmaxf(C, 1.f);
    }
  }
}

// ---------------- Launch: 2 dispatches total ----------------
extern "C" void kernel_launch(void* const* d_in, const int* in_sizes, int n_in,
                              void* d_out, int out_size, void* d_ws, size_t ws_size,
                              hipStream_t stream) {
  const float* emb = (const float*)d_in[0];
  const int* cats = (const int*)d_in[1];
  // d_in[2] (font_labels) is unused by the reference.
  float* out = (float*)d_out;

  char* ws = (char*)d_ws;
  float* accv = (float*)ws;                                  // loss, cnt, ctr1, ctr2
  unsigned short* ebf = (unsigned short*)(ws + 256);         // 4 MB bf16 normalized
  float* posP = (float*)(ws + 256 + NROWS * DDIM * 2);       // 16 strips x 8192
  float* sumP = posP + NSTRIPS * NROWS;

  knorm<<<NROWS / 4, 256, 0, stream>>>(emb, ebf, accv);
  kmain<<<dim3(NSTRIPS, NROWS / BM), 256, 0, stream>>>(ebf, cats, posP, sumP, accv, out);
}

// Round 5
// 167.809 us; speedup vs baseline: 1.4779x; 1.4779x over previous
//
#include <hip/hip_runtime.h>
#include <stdint.h>

// Problem constants (fixed by setup_inputs)
#define NROWS 8192
#define DDIM 256
#define TB 64                  // 64 row/col blocks of BM=128
#define BM 128                 // rows per block (4 waves x 32 rows)
#define NSLOTS TB              // partial slots per row
#define NWORK 2080             // TB*(TB+1)/2 working blocks (triangle)
#define NMERGE 32              // last-arriving blocks do the merge
#define BN 32                  // cols per LDS tile
#define NTILES 4               // BM / BN

// Scores are computed directly in log2-units: e is scaled by sqrt(log2(e)/0.7)
// so acc = s*log2(e) and exp(s) == exp2(acc). Since s <= 1/0.7, exp2(acc) <= 4.17:
// no overflow, so no log-sum-exp shift is needed anywhere.
#define ESCALE 1.4356159f      // sqrt(log2(e)/0.7)
#define LN2F   0.6931471806f
#define NEGBIG (-1e30f)

typedef __attribute__((ext_vector_type(8))) short short8;   // 8 bf16 = 4 VGPRs
typedef __attribute__((ext_vector_type(4))) float f32x4;    // MFMA 16x16 accumulator

typedef __attribute__((address_space(3))) void lds_void;        // LDS ptr for DMA builtin
typedef const __attribute__((address_space(1))) void gl_void;   // global ptr for DMA builtin

__device__ __forceinline__ unsigned short f2bf(float x) {   // RNE float->bf16
  unsigned int u = __float_as_uint(x);
  u += 0x7fffu + ((u >> 16) & 1u);
  return (unsigned short)(u >> 16);
}

// ---------------- Kernel 1: row L2-normalize -> scaled bf16 (+ zero counters) ----------------
__global__ __launch_bounds__(256) void knorm(const float* __restrict__ emb,
                                             unsigned short* __restrict__ ebf,
                                             float* __restrict__ accv) {
  if (blockIdx.x == 0 && threadIdx.x < 4) accv[threadIdx.x] = 0.f;  // loss,cnt,ctr1,ctr2
  const int wave = threadIdx.x >> 6, lane = threadIdx.x & 63;
  const int row = blockIdx.x * 4 + wave;              // one wave per row
  const float4 v = *(const float4*)(emb + row * DDIM + lane * 4);
  float ss = v.x * v.x + v.y * v.y + v.z * v.z + v.w * v.w;
#pragma unroll
  for (int off = 1; off < 64; off <<= 1) ss += __shfl_xor(ss, off, 64);
  const float sc = rsqrtf(ss) * ESCALE;
  ushort4 o;
  o.x = f2bf(v.x * sc); o.y = f2bf(v.y * sc);
  o.z = f2bf(v.z * sc); o.w = f2bf(v.w * sc);
  *(ushort4*)(ebf + row * DDIM + lane * 4) = o;
}

// ---------------- Kernel 2: symmetric (triangle) fused sims + masks + tail merge ----------------
// Each unordered block-pair {tr,tc} of 128x128 is computed ONCE. Row-stats go to
// rows of tr (slot tc); since sims is symmetric and the same-category mask is
// symmetric, the identical psv/ev values also give col-stats -> rows of tc
// (slot tr). Diagonal blocks (tr==tc) contribute row-stats only (slot tr).
// B staged via global_load_lds (round-3 verified layout), double-buffered.
__global__ __launch_bounds__(256) void kmain(const unsigned short* __restrict__ ebf,
                                             const int* __restrict__ cats,
                                             float* __restrict__ posP,
                                             float* __restrict__ sumP,
                                             float* __restrict__ accv,
                                             float* __restrict__ out) {
  __shared__ alignas(16) unsigned short smem[2][BN * DDIM];  // 2 x 16 KB
  __shared__ float cbufM[4 * BM], cbufS[4 * BM];             // col-stat wave combine (4 KB)
  __shared__ int sPrev;

  const int tid = threadIdx.x;
  const int lane = tid & 63, wave = tid >> 6;
  const int lane15 = lane & 15, quad = lane >> 4;

  // Circulant triangle mapping: y=0 diagonal; y in [1,31]: pair (x,(x+y)&63);
  // y=32: offset-32 pairs, x<32 only (x>=32 idle).
  const int x = blockIdx.x, y = blockIdx.y;
  int tr, tc;
  if (y == 32) { if (x >= 32) return; tr = x; tc = x + 32; }
  else { tr = x; tc = (x + y) & 63; }
  const bool isDiag = (tr == tc);
  const int rowG = tr * BM + wave * 32;               // this wave's 32 rows (mt=2)
  const int col0 = tc * BM;

  // A fragments in registers: A[m=lane&15][k=quad*8+j]
  short8 a[2][8];
#pragma unroll
  for (int m = 0; m < 2; ++m)
#pragma unroll
    for (int kk = 0; kk < 8; ++kk)
      a[m][kk] = *(const short8*)(ebf + (rowG + m * 16 + lane15) * DDIM + kk * 32 + quad * 8);

  // Row categories (C-layout rows = quad*4+r) and all 8 subtiles' col categories.
  int cati[2][4];
#pragma unroll
  for (int m = 0; m < 2; ++m)
#pragma unroll
    for (int r = 0; r < 4; ++r)
      cati[m][r] = cats[rowG + m * 16 + quad * 4 + r];
  int cj8[8];
#pragma unroll
  for (int ci = 0; ci < 8; ++ci) cj8[ci] = cats[col0 + ci * 16 + lane15];

  float pm[2][4], ns[2][4];                           // row-direction stats
#pragma unroll
  for (int m = 0; m < 2; ++m)
#pragma unroll
    for (int r = 0; r < 4; ++r) { pm[m][r] = NEGBIG; ns[m][r] = 0.f; }
  float cpm[8], cps[8];                               // col-direction stats per subtile
#pragma unroll
  for (int ci = 0; ci < 8; ++ci) { cpm[ci] = NEGBIG; cps[ci] = 0.f; }

  // Async-stage one B tile (1024 16B chunks, chunk p = kc*32+col at byte p*16):
  // 4 DMA/thread; LDS dest = wave-uniform (c*4096 + wave*1024) + lane*16.
#define STAGE(t, buf)                                                           \
  {                                                                             \
    const unsigned short* g = ebf +                                             \
        (size_t)(col0 + (t) * BN + (lane & 31)) * DDIM +                        \
        (wave * 2 + (lane >> 5)) * 8;                                           \
    char* lb = (char*)&smem[(buf)][0] + wave * 1024;                            \
    _Pragma("unroll")                                                           \
    for (int c = 0; c < 4; ++c)                                                 \
      __builtin_amdgcn_global_load_lds((gl_void*)(g + c * 64),                  \
                                       (lds_void*)(lb + c * 4096), 16, 0, 0);   \
  }

  STAGE(0, 0);

#pragma unroll
  for (int t = 0; t < NTILES; ++t) {
    __syncthreads();                       // tile t's DMA drained; prev reads done
    if (t + 1 < NTILES) STAGE(t + 1, (t + 1) & 1);   // overlaps this tile's MFMA
    const char* bb = (const char*)&smem[t & 1][0];
    const int colBase = col0 + t * BN;

#pragma unroll
    for (int nt = 0; nt < 2; ++nt) {
      f32x4 acc0 = {0.f, 0.f, 0.f, 0.f}, acc1 = {0.f, 0.f, 0.f, 0.f};
#pragma unroll
      for (int kk = 0; kk < 8; ++kk) {
        // B[k=quad*8+j][n=lane15] -> chunk (kc=kk*4+quad, col=nt*16+n)
        short8 b = *(const short8*)(bb + kk * 2048 + quad * 512 + nt * 256 + lane15 * 16);
        acc0 = __builtin_amdgcn_mfma_f32_16x16x32_bf16(a[0][kk], b, acc0, 0, 0, 0);
        acc1 = __builtin_amdgcn_mfma_f32_16x16x32_bf16(a[1][kk], b, acc1, 0, 0, 0);
      }
      const int ci = t * 2 + nt;
      const int cj = cj8[ci];
#pragma unroll
      for (int m = 0; m < 2; ++m) {
        const bool dg = (rowG + m * 16 == colBase + nt * 16);  // wave-uniform
        float psv[4], ev[4];
#pragma unroll
        for (int r = 0; r < 4; ++r) {
          const float s = m ? acc1[r] : acc0[r];      // score in log2-units
          const bool same = (cj == cati[m][r]);
          psv[r] = same ? s : NEGBIG;                 // positive candidate (both dirs)
          ev[r] = same ? 0.f : __builtin_amdgcn_exp2f(s);  // negative exp (both dirs)
        }
        if (dg) {                                     // rare: self-exclude on diagonal
#pragma unroll
          for (int r = 0; r < 4; ++r)
            if (lane15 == quad * 4 + r) psv[r] = NEGBIG;
        }
#pragma unroll
        for (int r = 0; r < 4; ++r) {
          pm[m][r] = fmaxf(pm[m][r], psv[r]);
          ns[m][r] += ev[r];
          cpm[ci] = fmaxf(cpm[ci], psv[r]);           // col direction: same values
          cps[ci] += ev[r];
        }
      }
    }
  }

  // Row-stats: reduce across the 16 lanes of each quad, store slot tc.
#pragma unroll
  for (int off = 1; off < 16; off <<= 1) {
#pragma unroll
    for (int m = 0; m < 2; ++m)
#pragma unroll
      for (int r = 0; r < 4; ++r) {
        pm[m][r] = fmaxf(pm[m][r], __shfl_xor(pm[m][r], off, 64));
        ns[m][r] += __shfl_xor(ns[m][r], off, 64);
      }
  }
  if (lane15 == 0) {
#pragma unroll
    for (int m = 0; m < 2; ++m)
#pragma unroll
      for (int r = 0; r < 4; ++r) {
        const int row = rowG + m * 16 + quad * 4 + r;
        posP[tc * NROWS + row] = pm[m][r];
        sumP[tc * NROWS + row] = ns[m][r];
      }
  }

  // Col-stats: reduce across quads (lanes sharing lane15), combine waves, slot tr.
  if (!isDiag) {
#pragma unroll
    for (int ci = 0; ci < 8; ++ci) {
      float cm = cpm[ci], cs = cps[ci];
      cm = fmaxf(cm, __shfl_xor(cm, 16, 64)); cm = fmaxf(cm, __shfl_xor(cm, 32, 64));
      cs += __shfl_xor(cs, 16, 64);           cs += __shfl_xor(cs, 32, 64);
      if (lane < 16) {
        cbufM[wave * BM + ci * 16 + lane15] = cm;
        cbufS[wave * BM + ci * 16 + lane15] = cs;
      }
    }
    __syncthreads();
    if (tid < BM) {
      const float cm = fmaxf(fmaxf(cbufM[tid], cbufM[BM + tid]),
                             fmaxf(cbufM[2 * BM + tid], cbufM[3 * BM + tid]));
      const float cs = cbufS[tid] + cbufS[BM + tid] + cbufS[2 * BM + tid] + cbufS[3 * BM + tid];
      posP[tr * NROWS + col0 + tid] = cm;
      sumP[tr * NROWS + col0 + tid] = cs;
    }
  }

  // ---- tail: last NMERGE arriving blocks merge 64 slots/row and finalize ----
  __syncthreads();                        // all partial stores issued block-wide
  if (tid == 0) {
    __threadfence();                      // release partials device-wide
    sPrev = atomicAdd((int*)(accv + 2), 1);
  }
  __syncthreads();
  const int prev = sPrev;
  if (prev < NWORK - NMERGE) return;      // early blocks exit
  const int rank = prev - (NWORK - NMERGE);
  if (tid == 0) {
    while (atomicAdd((int*)(accv + 2), 0) < NWORK) __builtin_amdgcn_s_sleep(2);
  }
  __syncthreads();
  __threadfence();

  const int row = rank * 256 + tid;       // NMERGE*256 == NROWS
  float pmv = NEGBIG, nsv = 0.f;
#pragma unroll 16
  for (int s = 0; s < NSLOTS; ++s) {      // atomic reads: coherent across XCDs
    pmv = fmaxf(pmv, atomicAdd(posP + s * NROWS + row, 0.f));
    nsv += atomicAdd(sumP + s * NROWS + row, 0.f);
  }
  const bool valid = (pmv > -1e29f) && (nsv > 0.f);
  // pmv is pos*log2(e); loss = ln(exp2(pmv) + sum_neg) - pmv*ln2
  float loss = valid ? (logf(__builtin_amdgcn_exp2f(pmv) + nsv) - pmv * LN2F) : 0.f;
  float cnt = valid ? 1.f : 0.f;
#pragma unroll
  for (int off = 1; off < 64; off <<= 1) {
    loss += __shfl_xor(loss, off, 64);
    cnt += __shfl_xor(cnt, off, 64);
  }
  if (lane == 0) {
    atomicAdd(&accv[0], loss);
    atomicAdd(&accv[1], cnt);
  }
  __syncthreads();
  if (tid == 0) {
    __threadfence();
    const int p2 = atomicAdd((int*)(accv + 3), 1);
    if (p2 == NMERGE - 1) {               // very last block writes the scalar
      const float L = atomicAdd(&accv[0], 0.f);
      const float C = atomicAdd(&accv[1], 0.f);
      out[0] = L / fmaxf(C, 1.f);
    }
  }
}

// ---------------- Launch: 2 dispatches total ----------------
extern "C" void kernel_launch(void* const* d_in, const int* in_sizes, int n_in,
                              void* d_out, int out_size, void* d_ws, size_t ws_size,
                              hipStream_t stream) {
  const float* emb = (const float*)d_in[0];
  const int* cats = (const int*)d_in[1];
  // d_in[2] (font_labels) is unused by the reference.
  float* out = (float*)d_out;

  char* ws = (char*)d_ws;
  float* accv = (float*)ws;                                  // loss, cnt, ctr1, ctr2
  unsigned short* ebf = (unsigned short*)(ws + 256);         // 4 MB bf16 normalized
  float* posP = (float*)(ws + 256 + NROWS * DDIM * 2);       // 64 slots x 8192 (2 MB)
  float* sumP = posP + NSLOTS * NROWS;                       // 2 MB

  knorm<<<NROWS / 4, 256, 0, stream>>>(emb, ebf, accv);
  kmain<<<dim3(TB, TB / 2 + 1), 256, 0, stream>>>(ebf, cats, posP, sumP, accv, out);
}

// Round 6
// 144.315 us; speedup vs baseline: 1.7185x; 1.1628x over previous
//
#include <hip/hip_runtime.h>
#include <stdint.h>

// Problem constants (fixed by setup_inputs)
#define NROWS 8192
#define DDIM 256
#define NSUP 16                // 16 supers of 512 rows
#define SUP 512
#define BM 128                 // rows per block (4 waves x 32 rows)
#define BN 32                  // cols per LDS tile
#define NTILES 16              // SUP / BN  (round-3-depth K loop)
#define NWORK 544              // 136 triangle supers x 4 blocks
#define NMERGE 32              // last-arriving blocks do the merge
#define RSLOTS 16              // row-stat slots (indexed by super-col j)
#define TSLOTS 76              // 16 row slots + 15*4 col slots

// Scores are computed directly in log2-units: e is scaled by sqrt(log2(e)/0.7)
// so acc = s*log2(e) and exp(s) == exp2(acc). Since s <= 1/0.7, exp2(acc) <= 4.17:
// no overflow, so no log-sum-exp shift is needed anywhere.
#define ESCALE 1.4356159f      // sqrt(log2(e)/0.7)
#define LN2F   0.6931471806f
#define NEGBIG (-1e30f)

typedef __attribute__((ext_vector_type(8))) short short8;   // 8 bf16 = 4 VGPRs
typedef __attribute__((ext_vector_type(4))) float f32x4;    // MFMA 16x16 accumulator

typedef __attribute__((address_space(3))) void lds_void;        // LDS ptr for DMA builtin
typedef const __attribute__((address_space(1))) void gl_void;   // global ptr for DMA builtin

__device__ __forceinline__ unsigned short f2bf(float x) {   // RNE float->bf16
  unsigned int u = __float_as_uint(x);
  u += 0x7fffu + ((u >> 16) & 1u);
  return (unsigned short)(u >> 16);
}

// ---------------- Kernel 1: row L2-normalize -> scaled bf16 (+ zero counters) ----------------
__global__ __launch_bounds__(256) void knorm(const float* __restrict__ emb,
                                             unsigned short* __restrict__ ebf,
                                             float* __restrict__ accv) {
  if (blockIdx.x == 0 && threadIdx.x < 4) accv[threadIdx.x] = 0.f;  // loss,cnt,ctr1,ctr2
  const int wave = threadIdx.x >> 6, lane = threadIdx.x & 63;
  const int row = blockIdx.x * 4 + wave;              // one wave per row
  const float4 v = *(const float4*)(emb + row * DDIM + lane * 4);
  float ss = v.x * v.x + v.y * v.y + v.z * v.z + v.w * v.w;
#pragma unroll
  for (int off = 1; off < 64; off <<= 1) ss += __shfl_xor(ss, off, 64);
  const float sc = rsqrtf(ss) * ESCALE;
  ushort4 o;
  o.x = f2bf(v.x * sc); o.y = f2bf(v.y * sc);
  o.z = f2bf(v.z * sc); o.w = f2bf(v.w * sc);
  *(ushort4*)(ebf + row * DDIM + lane * 4) = o;
}

// ---------------- Kernel 2: triangle-symmetric fused sims + masks + tail merge ----------------
// Triangle over 512x512 supers (i<=j), 4 blocks per super, each block = 128 rows
// x 512 cols with the round-3 16-deep double-buffered global_load_lds K-loop.
// Row-stats (for the 128 A-rows over 512 cols) -> slot j. Off-diagonal blocks also
// emit col-stats (identical psv/ev by symmetry) for the 512 cols reduced over the
// 128 A-rows -> slot 16+i*4+b. Diagonal supers: row-stats only (full square done).
__global__ __launch_bounds__(256) void kmain(const unsigned short* __restrict__ ebf,
                                             const int* __restrict__ cats,
                                             float* __restrict__ posP,
                                             float* __restrict__ sumP,
                                             float* __restrict__ accv,
                                             float* __restrict__ out) {
  __shared__ alignas(16) unsigned short smem[2][BN * DDIM];  // 2 x 16 KB
  __shared__ float cbufM[4 * SUP], cbufS[4 * SUP];           // per-wave col-stats (16 KB)
  __shared__ int sPrev;

  const int tid = threadIdx.x;
  const int lane = tid & 63, wave = tid >> 6;
  const int lane15 = lane & 15, quad = lane >> 4;

  // Decode triangle super (i,j), i<=j, from blockIdx.x in [0,136).
  int srem = blockIdx.x, i = 0;
  while (srem >= NSUP - i) { srem -= NSUP - i; ++i; }
  const int j = i + srem;
  const int b = blockIdx.y;                           // sub-row 0..3 within super i
  const bool offd = (i != j);
  const int rowG = i * SUP + b * BM + wave * 32;      // this wave's 32 rows (mt=2)
  const int col0 = j * SUP;

  // A fragments in registers all kernel: A[m=lane&15][k=quad*8+j]
  short8 a[2][8];
#pragma unroll
  for (int m = 0; m < 2; ++m)
#pragma unroll
    for (int kk = 0; kk < 8; ++kk)
      a[m][kk] = *(const short8*)(ebf + (rowG + m * 16 + lane15) * DDIM + kk * 32 + quad * 8);

  // Row categories (C-layout rows = quad*4+r)
  int cati[2][4];
#pragma unroll
  for (int m = 0; m < 2; ++m)
#pragma unroll
    for (int r = 0; r < 4; ++r)
      cati[m][r] = cats[rowG + m * 16 + quad * 4 + r];

  float pm[2][4], ns[2][4];                           // row-direction stats
#pragma unroll
  for (int m = 0; m < 2; ++m)
#pragma unroll
    for (int r = 0; r < 4; ++r) { pm[m][r] = NEGBIG; ns[m][r] = 0.f; }

  // Async-stage one B tile (1024 16B chunks, chunk p = kc*32+col at byte p*16):
  // 4 DMA/thread; LDS dest = wave-uniform (c*4096 + wave*1024) + lane*16.
#define STAGE(t, buf)                                                           \
  {                                                                             \
    const unsigned short* g = ebf +                                             \
        (size_t)(col0 + (t) * BN + (lane & 31)) * DDIM +                        \
        (wave * 2 + (lane >> 5)) * 8;                                           \
    char* lb = (char*)&smem[(buf)][0] + wave * 1024;                            \
    _Pragma("unroll")                                                           \
    for (int c = 0; c < 4; ++c)                                                 \
      __builtin_amdgcn_global_load_lds((gl_void*)(g + c * 64),                  \
                                       (lds_void*)(lb + c * 4096), 16, 0, 0);   \
  }

  STAGE(0, 0);

  for (int t = 0; t < NTILES; ++t) {
    __syncthreads();                       // tile t's DMA drained; prev reads done
    if (t + 1 < NTILES) STAGE(t + 1, (t + 1) & 1);   // overlaps this tile's MFMA
    const char* bb = (const char*)&smem[t & 1][0];
    const int colBase = col0 + t * BN;
    const int cjt[2] = {cats[colBase + lane15], cats[colBase + 16 + lane15]};

#pragma unroll
    for (int nt = 0; nt < 2; ++nt) {
      f32x4 acc0 = {0.f, 0.f, 0.f, 0.f}, acc1 = {0.f, 0.f, 0.f, 0.f};
#pragma unroll
      for (int kk = 0; kk < 8; ++kk) {
        // B[k=quad*8+j][n=lane15] -> chunk (kc=kk*4+quad, col=nt*16+n)
        short8 bfr = *(const short8*)(bb + kk * 2048 + quad * 512 + nt * 256 + lane15 * 16);
        acc0 = __builtin_amdgcn_mfma_f32_16x16x32_bf16(a[0][kk], bfr, acc0, 0, 0, 0);
        acc1 = __builtin_amdgcn_mfma_f32_16x16x32_bf16(a[1][kk], bfr, acc1, 0, 0, 0);
      }
      const int cj = cjt[nt];
      float cm = NEGBIG, cs = 0.f;                    // col-direction partial (this lane's col)
#pragma unroll
      for (int m = 0; m < 2; ++m) {
        const bool dg = (rowG + m * 16 == colBase + nt * 16);  // wave-uniform: diagonal tile?
        float psv[4], ev[4];
#pragma unroll
        for (int r = 0; r < 4; ++r) {
          const float s = m ? acc1[r] : acc0[r];      // score in log2-units
          const bool same = (cj == cati[m][r]);
          psv[r] = same ? s : NEGBIG;                 // positive candidate (both dirs)
          ev[r] = same ? 0.f : __builtin_amdgcn_exp2f(s);  // negative exp (both dirs)
        }
        if (dg) {                                     // rare: self-exclude on diagonal
#pragma unroll
          for (int r = 0; r < 4; ++r)
            if (lane15 == quad * 4 + r) psv[r] = NEGBIG;
        }
#pragma unroll
        for (int r = 0; r < 4; ++r) {
          pm[m][r] = fmaxf(pm[m][r], psv[r]);
          ns[m][r] += ev[r];
          cm = fmaxf(cm, psv[r]);                     // symmetric: same values, col dir
          cs += ev[r];
        }
      }
      // Reduce col-stats across the 4 quads (lanes sharing lane15), park in LDS.
      cm = fmaxf(cm, __shfl_xor(cm, 16, 64)); cm = fmaxf(cm, __shfl_xor(cm, 32, 64));
      cs += __shfl_xor(cs, 16, 64);           cs += __shfl_xor(cs, 32, 64);
      if (offd && lane < 16) {
        const int ci = t * 2 + nt;                    // subtile 0..31
        cbufM[wave * SUP + ci * 16 + lane15] = cm;
        cbufS[wave * SUP + ci * 16 + lane15] = cs;
      }
    }
  }

  // Row-stats: reduce across the 16 lanes of each quad, store slot j.
#pragma unroll
  for (int off = 1; off < 16; off <<= 1) {
#pragma unroll
    for (int m = 0; m < 2; ++m)
#pragma unroll
      for (int r = 0; r < 4; ++r) {
        pm[m][r] = fmaxf(pm[m][r], __shfl_xor(pm[m][r], off, 64));
        ns[m][r] += __shfl_xor(ns[m][r], off, 64);
      }
  }
  if (lane15 == 0) {
#pragma unroll
    for (int m = 0; m < 2; ++m)
#pragma unroll
      for (int r = 0; r < 4; ++r) {
        const int row = rowG + m * 16 + quad * 4 + r;
        posP[j * NROWS + row] = pm[m][r];
        sumP[j * NROWS + row] = ns[m][r];
      }
  }

  // Col-stats: combine the 4 waves' partials, store slot 16+i*4+b (off-diag only).
  if (offd) {
    __syncthreads();
    const int slot = RSLOTS + i * 4 + b;
#pragma unroll
    for (int c2 = 0; c2 < 2; ++c2) {
      const int c = c2 * 256 + tid;                   // 512 cols by 256 threads
      const float cm = fmaxf(fmaxf(cbufM[c], cbufM[SUP + c]),
                             fmaxf(cbufM[2 * SUP + c], cbufM[3 * SUP + c]));
      const float cs = cbufS[c] + cbufS[SUP + c] + cbufS[2 * SUP + c] + cbufS[3 * SUP + c];
      posP[slot * NROWS + col0 + c] = cm;
      sumP[slot * NROWS + col0 + c] = cs;
    }
  }

  // ---- tail: last NMERGE arriving blocks merge and finalize ----
  __syncthreads();                        // all partial stores issued block-wide
  if (tid == 0) {
    __threadfence();                      // release partials device-wide
    sPrev = atomicAdd((int*)(accv + 2), 1);
  }
  __syncthreads();
  const int prev = sPrev;
  if (prev < NWORK - NMERGE) return;      // early blocks exit
  const int rank = prev - (NWORK - NMERGE);
  if (tid == 0) {
    while (atomicAdd((int*)(accv + 2), 0) < NWORK) __builtin_amdgcn_s_sleep(2);
  }
  __syncthreads();
  __threadfence();                        // acquire: partials now visible

  const int row = rank * 256 + tid;       // NMERGE*256 == NROWS
  const int r = row >> 9;                 // this row's super (uniform per block)
  float pmv = NEGBIG, nsv = 0.f;
  for (int sl = r; sl < RSLOTS; ++sl) {   // row-stat slots j >= r
    pmv = fmaxf(pmv, posP[sl * NROWS + row]);
    nsv += sumP[sl * NROWS + row];
  }
  const int ce = RSLOTS + 4 * r;          // col-stat slots from supers i < r
  for (int sl = RSLOTS; sl < ce; ++sl) {
    pmv = fmaxf(pmv, posP[sl * NROWS + row]);
    nsv += sumP[sl * NROWS + row];
  }
  const bool valid = (pmv > -1e29f) && (nsv > 0.f);
  // pmv is pos*log2(e); loss = ln(exp2(pmv) + sum_neg) - pmv*ln2
  float loss = valid ? (logf(__builtin_amdgcn_exp2f(pmv) + nsv) - pmv * LN2F) : 0.f;
  float cnt = valid ? 1.f : 0.f;
#pragma unroll
  for (int off = 1; off < 64; off <<= 1) {
    loss += __shfl_xor(loss, off, 64);
    cnt += __shfl_xor(cnt, off, 64);
  }
  if (lane == 0) {
    atomicAdd(&accv[0], loss);
    atomicAdd(&accv[1], cnt);
  }
  __syncthreads();
  if (tid == 0) {
    __threadfence();
    const int p2 = atomicAdd((int*)(accv + 3), 1);
    if (p2 == NMERGE - 1) {               // very last block writes the scalar
      const float L = atomicAdd(&accv[0], 0.f);
      const float C = atomicAdd(&accv[1], 0.f);
      out[0] = L / fmaxf(C, 1.f);
    }
  }
}

// ---------------- Launch: 2 dispatches total ----------------
extern "C" void kernel_launch(void* const* d_in, const int* in_sizes, int n_in,
                              void* d_out, int out_size, void* d_ws, size_t ws_size,
                              hipStream_t stream) {
  const float* emb = (const float*)d_in[0];
  const int* cats = (const int*)d_in[1];
  // d_in[2] (font_labels) is unused by the reference.
  float* out = (float*)d_out;

  char* ws = (char*)d_ws;
  float* accv = (float*)ws;                                  // loss, cnt, ctr1, ctr2
  unsigned short* ebf = (unsigned short*)(ws + 256);         // 4 MB bf16 normalized
  float* posP = (float*)(ws + 256 + NROWS * DDIM * 2);       // 76 slots x 8192 (2.49 MB)
  float* sumP = posP + TSLOTS * NROWS;                       // 2.49 MB

  knorm<<<NROWS / 4, 256, 0, stream>>>(emb, ebf, accv);
  kmain<<<dim3(136, 4), 256, 0, stream>>>(ebf, cats, posP, sumP, accv, out);
}